// Round 9
// baseline (113.735 us; speedup 1.0000x reference)
//
#include <hip/hip_runtime.h>

#define N_NODES 100000
#define N_EDGES 3200000
// 3125 blocks x 256 threads x 4 edges = 3,200,000 exactly -> no tail.

typedef float f4_t __attribute__((ext_vector_type(4)));
typedef float f2_t __attribute__((ext_vector_type(2)));

// EXACT R5 structure (nt stores); single change: node gathers are
// NONTEMPORAL loads (no L1 allocate) -- A/B probing whether divergent-gather
// cost is L1 allocate/evict churn vs TA address-issue.
__global__ __launch_bounds__(256) void gnn_fused_kernel(
    const float* __restrict__ node, const float* __restrict__ edge,
    const int* __restrict__ ei,
    const float* __restrict__ We, const float* __restrict__ be,
    const float* __restrict__ Wu, const float* __restrict__ bu,
    const float* __restrict__ Wn, const float* __restrict__ bn,
    float* __restrict__ out, float* __restrict__ ef_out)
{
    __shared__ float wf[4][80];          // per-wave folded weights: [8*h + j]
    __shared__ float stg[4][64 * 21];    // per-wave staging, stride 21 (gcd(21,32)=1)

    const int tid   = threadIdx.x;
    const int lane  = tid & 63;
    const int wslot = tid >> 6;
    const int T     = blockIdx.x * 256 + tid;
    const int gwave = blockIdx.x * 4 + wslot;
    const size_t E0 = (size_t)gwave * 256;     // wave's first edge

    // ---- uniform layout detection: int64 (LE, <2^31) => odd dwords are 0 ----
    const bool is64 = (ei[1] == 0) & (ei[3] == 0) & (ei[5] == 0) & (ei[7] == 0);

    // ---- issue all independent global loads up front ----
    float4 eA = ((const float4*)edge)[E0 / 2 + lane];        // edges E0+2l, E0+2l+1
    float4 eB = ((const float4*)edge)[E0 / 2 + 64 + lane];   // edges E0+128+2l, +1

    int r0, r1, r2, r3, c0, c1, c2, c3;
    if (is64) {
        const int4* R = (const int4*)ei;                       // int64 lows at .x,.z
        const int4* C = (const int4*)(ei + 2 * (size_t)N_EDGES);
        int4 ra = R[E0 / 2 + lane], rb = R[E0 / 2 + 64 + lane];
        int4 ca = C[E0 / 2 + lane], cb = C[E0 / 2 + 64 + lane];
        r0 = ra.x; r1 = ra.z; r2 = rb.x; r3 = rb.z;
        c0 = ca.x; c1 = ca.z; c2 = cb.x; c3 = cb.z;
    } else {
        const int2* R = (const int2*)ei;
        const int2* C = (const int2*)(ei + (size_t)N_EDGES);
        int2 ra = R[E0 / 2 + lane], rb = R[E0 / 2 + 64 + lane];
        int2 ca = C[E0 / 2 + lane], cb = C[E0 / 2 + 64 + lane];
        r0 = ra.x; r1 = ra.y; r2 = rb.x; r3 = rb.y;
        c0 = ca.x; c1 = ca.y; c2 = cb.x; c3 = cb.y;
    }

    // ---- node branch: out = node @ Wn + bn (800K threads cover 100K nodes) ----
    if (T < N_NODES) {
        float2 nf = ((const float2*)node)[T];
        float o0 = fmaf(nf.y, Wn[2], fmaf(nf.x, Wn[0], bn[0]));
        float o1 = fmaf(nf.y, Wn[3], fmaf(nf.x, Wn[1], bn[1]));
        ((float2*)out)[T] = make_float2(o0, o1);
    }

    // ---- per-wave fold: Weff = [We@Wu_e ; Wu_nodes], Ceff = be@Wu_e + bu ----
    if (lane < 60) {
        int r = lane / 10, h = lane % 10;
        float v;
        if (r < 2) {
            v = 0.0f;
            #pragma unroll
            for (int k = 0; k < 10; ++k) v = fmaf(We[r * 10 + k], Wu[k * 10 + h], v);
        } else {
            v = Wu[(10 + (r - 2)) * 10 + h];
        }
        wf[wslot][8 * h + r] = v;
    }
    if (lane < 10) {
        int h = lane;
        float v = bu[h];
        #pragma unroll
        for (int k = 0; k < 10; ++k) v = fmaf(be[k], Wu[k * 10 + h], v);
        wf[wslot][8 * h + 6] = v;
    }
    __builtin_amdgcn_wave_barrier();

    // ---- gathers: NONTEMPORAL (no L1 allocate), all independent/in flight ----
    const f2_t* nodev = (const f2_t*)node;
    f2_t s0 = __builtin_nontemporal_load(&nodev[r0]);
    f2_t d0 = __builtin_nontemporal_load(&nodev[c0]);
    f2_t s1 = __builtin_nontemporal_load(&nodev[r1]);
    f2_t d1 = __builtin_nontemporal_load(&nodev[c1]);
    f2_t s2 = __builtin_nontemporal_load(&nodev[r2]);
    f2_t d2 = __builtin_nontemporal_load(&nodev[c2]);
    f2_t s3 = __builtin_nontemporal_load(&nodev[r3]);
    f2_t d3 = __builtin_nontemporal_load(&nodev[c3]);

    float* S = &stg[wslot][0];
    const float* WF = &wf[wslot][0];
    f4_t* g4 = (f4_t*)ef_out + (size_t)gwave * 640;   // wave's 256-edge span

    // ================= round A: edges E0+2l, E0+2l+1 =================
    {
        float rr[20];
        #pragma unroll
        for (int h = 0; h < 10; ++h) {
            const f4_t* wv = (const f4_t*)&WF[8 * h];
            f4_t wa = wv[0];                    // e0,e1,s0,s1 coeffs
            f4_t wb = wv[1];                    // d0,d1,bias,pad
            float a0 = wb.z, a1 = wb.z;
            a0 = fmaf(eA.x, wa.x, a0);  a1 = fmaf(eA.z, wa.x, a1);
            a0 = fmaf(eA.y, wa.y, a0);  a1 = fmaf(eA.w, wa.y, a1);
            a0 = fmaf(s0.x, wa.z, a0);  a1 = fmaf(s1.x, wa.z, a1);
            a0 = fmaf(s0.y, wa.w, a0);  a1 = fmaf(s1.y, wa.w, a1);
            a0 = fmaf(d0.x, wb.x, a0);  a1 = fmaf(d1.x, wb.x, a1);
            a0 = fmaf(d0.y, wb.y, a0);  a1 = fmaf(d1.y, wb.y, a1);
            rr[h] = a0; rr[10 + h] = a1;
        }
        #pragma unroll
        for (int k = 0; k < 20; ++k) S[lane * 21 + k] = rr[k];
        __builtin_amdgcn_wave_barrier();
        #pragma unroll
        for (int v = 0; v < 5; ++v) {
            unsigned slot = v * 64 + lane;          // 0..319 float4 slots (1280 floats)
            unsigned p = slot / 5u, jj = slot - 5u * p;
            const float* src = &S[p * 21 + 4 * jj];
            f4_t w = { src[0], src[1], src[2], src[3] };
            __builtin_nontemporal_store(w, &g4[slot]);
        }
        __builtin_amdgcn_wave_barrier();
    }
    // ================= round B: edges E0+128+2l, +1 =================
    {
        float rr[20];
        #pragma unroll
        for (int h = 0; h < 10; ++h) {
            const f4_t* wv = (const f4_t*)&WF[8 * h];
            f4_t wa = wv[0];
            f4_t wb = wv[1];
            float a0 = wb.z, a1 = wb.z;
            a0 = fmaf(eB.x, wa.x, a0);  a1 = fmaf(eB.z, wa.x, a1);
            a0 = fmaf(eB.y, wa.y, a0);  a1 = fmaf(eB.w, wa.y, a1);
            a0 = fmaf(s2.x, wa.z, a0);  a1 = fmaf(s3.x, wa.z, a1);
            a0 = fmaf(s2.y, wa.w, a0);  a1 = fmaf(s3.y, wa.w, a1);
            a0 = fmaf(d2.x, wb.x, a0);  a1 = fmaf(d3.x, wb.x, a1);
            a0 = fmaf(d2.y, wb.y, a0);  a1 = fmaf(d3.y, wb.y, a1);
            rr[h] = a0; rr[10 + h] = a1;
        }
        #pragma unroll
        for (int k = 0; k < 20; ++k) S[lane * 21 + k] = rr[k];
        __builtin_amdgcn_wave_barrier();
        #pragma unroll
        for (int v = 0; v < 5; ++v) {
            unsigned slot = v * 64 + lane;
            unsigned p = slot / 5u, jj = slot - 5u * p;
            const float* src = &S[p * 21 + 4 * jj];
            f4_t w = { src[0], src[1], src[2], src[3] };
            __builtin_nontemporal_store(w, &g4[320 + slot]);
        }
    }
}

extern "C" void kernel_launch(void* const* d_in, const int* in_sizes, int n_in,
                              void* d_out, int out_size, void* d_ws, size_t ws_size,
                              hipStream_t stream) {
    const float* node = (const float*)d_in[0];
    const float* edge = (const float*)d_in[1];
    const int*   ei   = (const int*)d_in[2];
    const float* We   = (const float*)d_in[3];
    const float* be   = (const float*)d_in[4];
    const float* Wu   = (const float*)d_in[5];
    const float* bu   = (const float*)d_in[6];
    const float* Wn   = (const float*)d_in[7];
    const float* bn   = (const float*)d_in[8];

    float* out = (float*)d_out;
    float* ef  = out + 2 * (size_t)N_NODES;

    hipLaunchKernelGGL(gnn_fused_kernel, dim3(N_EDGES / 1024), dim3(256), 0, stream,
                       node, edge, ei, We, be, Wu, bu, Wn, bn, out, ef);
}

// Round 10
// 43.096 us; speedup vs baseline: 2.6391x; 2.6391x over previous
//
#include <hip/hip_runtime.h>

#define N_NODES 100000
#define N_EDGES 3200000
// EPT=2: 6250 blocks * 256 threads * 2 edges = 3200000 exactly -> no tail.

typedef float f4_t __attribute__((ext_vector_type(4)));

// Measured-best configuration (R4, 43.03 us): single fused kernel.
//   Phase A: edge load + node branch issued; threads 0..70 fold the 2-layer
//            edge MLP into Weff(6x10)+Ceff in LDS; int64-layout flag.
//   Phase B: index loads -> node gathers (PLAIN loads: L2-served) -> 60 FMA.
//   Phase C: stride-21 LDS staging -> block-contiguous NT float4 stores.
__global__ __launch_bounds__(256) void gnn_fused_kernel(
    const float* __restrict__ node, const float* __restrict__ edge,
    const int* __restrict__ ei,
    const float* __restrict__ We, const float* __restrict__ be,
    const float* __restrict__ Wu, const float* __restrict__ bu,
    const float* __restrict__ Wn, const float* __restrict__ bn,
    float* __restrict__ out, float* __restrict__ ef_out)
{
    __shared__ float wf2[80];        // [8*h + j]: j=0..5 Weff, j=6 Ceff
    __shared__ int   flagS;
    __shared__ float lds[256 * 21];  // stride 21: gcd(21,32)=1 -> <=2-way (free)

    const int tid = threadIdx.x;
    const int t = blockIdx.x * 256 + tid;     // pair index; edges 2t, 2t+1

    // ---- Phase A ----
    float4 e01 = ((const float4*)edge)[t];    // edge 2t: (x,y), edge 2t+1: (z,w)

    if (t < N_NODES) {                        // node branch: out = node @ Wn + bn
        float2 nf = ((const float2*)node)[t];
        float o0 = fmaf(nf.y, Wn[2], fmaf(nf.x, Wn[0], bn[0]));
        float o1 = fmaf(nf.y, Wn[3], fmaf(nf.x, Wn[1], bn[1]));
        ((float2*)out)[t] = make_float2(o0, o1);
    }

    // fold: Weff = [We@Wu_e ; Wu_nodes], Ceff = be@Wu_e + bu
    if (tid < 60) {
        int r = tid / 10, h = tid % 10;
        float v;
        if (r < 2) {
            v = 0.0f;
            #pragma unroll
            for (int k = 0; k < 10; ++k) v = fmaf(We[r * 10 + k], Wu[k * 10 + h], v);
        } else {
            v = Wu[(10 + (r - 2)) * 10 + h];
        }
        wf2[8 * h + r] = v;
    } else if (tid < 70) {
        int h = tid - 60;
        float v = bu[h];
        #pragma unroll
        for (int k = 0; k < 10; ++k) v = fmaf(be[k], Wu[k * 10 + h], v);
        wf2[8 * h + 6] = v;
    } else if (tid == 70) {
        // int64 edge_index (LE, values < 2^31) -> every odd int32 word is 0.
        flagS = (ei[1] == 0 && ei[3] == 0 && ei[5] == 0 && ei[7] == 0) ? 1 : 0;
    }
    __syncthreads();

    // ---- Phase B ----
    const int is64 = flagS;
    int row0, col0, row1, col1;
    if (is64) {
        int4 rr = ((const int4*)ei)[t];                       // int64 lows at .x,.z
        int4 cc = ((const int4*)(ei + 2 * (size_t)N_EDGES))[t];
        row0 = rr.x; row1 = rr.z; col0 = cc.x; col1 = cc.z;
    } else {
        int2 rr = ((const int2*)ei)[t];
        int2 cc = ((const int2*)(ei + (size_t)N_EDGES))[t];
        row0 = rr.x; row1 = rr.y; col0 = cc.x; col1 = cc.y;
    }

    float2 s0 = ((const float2*)node)[row0];   // PLAIN gathers -> L2-served
    float2 d0 = ((const float2*)node)[col0];
    float2 s1 = ((const float2*)node)[row1];
    float2 d1 = ((const float2*)node)[col1];

    float r[20];
    #pragma unroll
    for (int h = 0; h < 10; ++h) {
        const f4_t* wv = (const f4_t*)&wf2[8 * h];   // 32B-aligned broadcast reads
        f4_t wa = wv[0];                              // w0,w1,w2,w3
        f4_t wb = wv[1];                              // w4,w5,c,pad
        float a0 = wb.z, a1 = wb.z;
        a0 = fmaf(e01.x, wa.x, a0);  a1 = fmaf(e01.z, wa.x, a1);
        a0 = fmaf(e01.y, wa.y, a0);  a1 = fmaf(e01.w, wa.y, a1);
        a0 = fmaf(s0.x,  wa.z, a0);  a1 = fmaf(s1.x,  wa.z, a1);
        a0 = fmaf(s0.y,  wa.w, a0);  a1 = fmaf(s1.y,  wa.w, a1);
        a0 = fmaf(d0.x,  wb.x, a0);  a1 = fmaf(d1.x,  wb.x, a1);
        a0 = fmaf(d0.y,  wb.y, a0);  a1 = fmaf(d1.y,  wb.y, a1);
        r[h] = a0; r[10 + h] = a1;
    }

    // stage: thread's 20 outputs at stride-21 (banks ~conflict-free)
    #pragma unroll
    for (int k = 0; k < 10; ++k) lds[tid * 21 + k] = r[k];
    #pragma unroll
    for (int k = 0; k < 10; ++k) lds[tid * 21 + 10 + k] = r[10 + k];
    __syncthreads();

    // ---- Phase C: block output span 512 edges * 10 = 5120 floats, contiguous ----
    f4_t* g4 = (f4_t*)(ef_out + (size_t)blockIdx.x * 5120);
    #pragma unroll
    for (int v = 0; v < 5; ++v) {
        unsigned gidx = v * 256 + tid;        // float4 slot in block span
        unsigned p = gidx / 5u;               // source pair (thread) in LDS
        unsigned jj = gidx - 5u * p;          // float4-slot within that pair
        const float* src = &lds[p * 21 + 4 * jj];
        f4_t w = { src[0], src[1], src[2], src[3] };
        __builtin_nontemporal_store(w, &g4[gidx]);
    }
}

extern "C" void kernel_launch(void* const* d_in, const int* in_sizes, int n_in,
                              void* d_out, int out_size, void* d_ws, size_t ws_size,
                              hipStream_t stream) {
    const float* node = (const float*)d_in[0];
    const float* edge = (const float*)d_in[1];
    const int*   ei   = (const int*)d_in[2];
    const float* We   = (const float*)d_in[3];
    const float* be   = (const float*)d_in[4];
    const float* Wu   = (const float*)d_in[5];
    const float* bu   = (const float*)d_in[6];
    const float* Wn   = (const float*)d_in[7];
    const float* bn   = (const float*)d_in[8];

    float* out = (float*)d_out;
    float* ef  = out + 2 * (size_t)N_NODES;

    hipLaunchKernelGGL(gnn_fused_kernel, dim3(N_EDGES / 512), dim3(256), 0, stream,
                       node, edge, ei, We, be, Wu, bu, Wn, bn, out, ef);
}